// Round 21
// baseline (225.361 us; speedup 1.0000x reference)
//
#include <hip/hip_runtime.h>
#include <hip/hip_bf16.h>
#include <cstdint>

typedef unsigned short u16;
typedef unsigned int u32;
typedef __bf16 bf16x8 __attribute__((ext_vector_type(8)));
typedef float f32x4 __attribute__((ext_vector_type(4)));
typedef float f32x16 __attribute__((ext_vector_type(16)));

#define BATCH 2
#define SEQ 2048
#define DMODEL 2048
#define NH 32
#define NKVH 8
#define HD 64
#define NQROWS (BATCH*SEQ)   // 4096
#define QCOLS (NH*HD)        // 2048
#define KVCOLS (NKVH*HD)     // 512
#define NCAT (QCOLS+2*KVCOLS) // 3072

static __device__ __forceinline__ u16 f2bf(float f) {
  u32 u = __float_as_uint(f);
  return (u16)((u + 0x7fffu + ((u >> 16) & 1u)) >> 16);   // RNE
}

// async global->LDS, 16B per lane, wave-uniform LDS base + lane*16
#define GLOAD16(gp, lp) __builtin_amdgcn_global_load_lds( \
    (const __attribute__((address_space(1))) void*)(gp),  \
    (__attribute__((address_space(3))) void*)(lp), 16, 0, 0)

// ---------------- f32 -> bf16 convert ----------------
__global__ __launch_bounds__(256) void k_cvt_bf16(const float* __restrict__ in,
                                                  u16* __restrict__ out, int n4) {
  int i = blockIdx.x * 256 + threadIdx.x;
  if (i >= n4) return;
  float4 v = reinterpret_cast<const float4*>(in)[i];
  ushort4 o;
  o.x = f2bf(v.x); o.y = f2bf(v.y); o.z = f2bf(v.z); o.w = f2bf(v.w);
  reinterpret_cast<ushort4*>(out)[i] = o;
}

// ------- merged weight transposes: one launch for wq|wk|wv -> wcatT, wo -> woT
__global__ __launch_bounds__(256) void k_transpose_all(const float* __restrict__ wq,
                                                       const float* __restrict__ wk,
                                                       const float* __restrict__ wv,
                                                       const float* __restrict__ wo,
                                                       u16* __restrict__ wcatT,
                                                       u16* __restrict__ woT) {
  __shared__ float tile[32][33];
  const int tidx = blockIdx.x;
  const float* src; u16* dst; int C, c0, r0;
  if (tidx < 4096) {
    src = wq; dst = wcatT; C = QCOLS;
    c0 = (tidx & 63) * 32; r0 = (tidx >> 6) * 32;
  } else if (tidx < 5120) {
    int t2 = tidx - 4096;
    src = wk; dst = wcatT + (size_t)QCOLS * DMODEL; C = KVCOLS;
    c0 = (t2 & 15) * 32; r0 = (t2 >> 4) * 32;
  } else if (tidx < 6144) {
    int t2 = tidx - 5120;
    src = wv; dst = wcatT + (size_t)(QCOLS + KVCOLS) * DMODEL; C = KVCOLS;
    c0 = (t2 & 15) * 32; r0 = (t2 >> 4) * 32;
  } else {
    int t2 = tidx - 6144;
    src = wo; dst = woT; C = DMODEL;
    c0 = (t2 & 63) * 32; r0 = (t2 >> 6) * 32;
  }
  const int R = 2048;  // all sources have 2048 rows
  int tx = threadIdx.x & 31, ty = threadIdx.x >> 5;  // 32 x 8
#pragma unroll
  for (int i = 0; i < 4; i++)
    tile[ty * 4 + i][tx] = src[(size_t)(r0 + ty * 4 + i) * C + c0 + tx];
  __syncthreads();
#pragma unroll
  for (int i = 0; i < 4; i++)
    dst[(size_t)(c0 + ty * 4 + i) * R + r0 + tx] = f2bf(tile[tx][ty * 4 + i]);
}

// ---------------- bf16 GEMM: C[M][N] = A[M][K] * BT[N][K]^T ----------------
// 128x128 tile, BK=32, 4 waves each owning 64x64 (4x4 frags).
// 2-PHASE DBUF: stage(next K-tile) issued BEFORE current tile's compute;
// ONE __syncthreads per K-step. XCD-aware bijective block swizzle.
// EPI 1: f32 out.  EPI 3: fused QKV epilogue (Q RoPE+scale, K RoPE, V^T).
template<int EPI>
__global__ __launch_bounds__(256) void k_gemm(const u16* __restrict__ A,
                                              const u16* __restrict__ BT,
                                              void* __restrict__ Cout,
                                              int M, int N, int K,
                                              const float* __restrict__ cosb,
                                              const float* __restrict__ sinb,
                                              u16* __restrict__ dstK,
                                              u16* __restrict__ dstV) {
  __shared__ __align__(16) u16 As[2][128 * 32];
  __shared__ __align__(16) u16 Bs[2][128 * 32];
  const int tid = threadIdx.x;
  const int w = tid >> 6, l = tid & 63;
  const int l15 = l & 15, l4 = l >> 4;

  // XCD swizzle: hw id -> contiguous work chunk per XCD (nwg % 8 == 0)
  const int nwg = gridDim.x * gridDim.y;
  int hwid = blockIdx.y * gridDim.x + blockIdx.x;
  int wk = (hwid & 7) * (nwg >> 3) + (hwid >> 3);
  const int bx = wk % gridDim.x, by = wk / gridDim.x;

  const int m0 = by * 128, n0 = bx * 128;
  const int wr = w >> 1, wc = w & 1;

  const u16* ga = A + (size_t)(m0 + w * 32 + (l >> 2)) * K + (l & 3) * 8;
  const u16* gb = BT + (size_t)(n0 + w * 32 + (l >> 2)) * K + (l & 3) * 8;
  const int af_off = (wr * 64 + l15) * 32 + l4 * 8;
  const int bf_off = (wc * 64 + l15) * 32 + l4 * 8;

  auto stage = [&](int buf, int kt) {
    const u16* ga_ = ga + kt;
    const u16* gb_ = gb + kt;
    u16* asb = &As[buf][w * 1024];
    u16* bsb = &Bs[buf][w * 1024];
    GLOAD16(ga_, asb);
    GLOAD16(ga_ + 16 * (size_t)K, asb + 512);
    GLOAD16(gb_, bsb);
    GLOAD16(gb_ + 16 * (size_t)K, bsb + 512);
  };

  f32x4 acc[4][4] = {};
  stage(0, 0);
  __syncthreads();            // prologue: tile 0 resident

  int cur = 0;
  for (int kt = 0; kt < K; kt += 32) {
    if (kt + 32 < K) stage(cur ^ 1, kt + 32);   // prefetch next tile (async)
    bf16x8 af[4], bfv[4];
#pragma unroll
    for (int mi = 0; mi < 4; mi++)
      af[mi] = *reinterpret_cast<const bf16x8*>(&As[cur][af_off + mi * 512]);
#pragma unroll
    for (int ni = 0; ni < 4; ni++)
      bfv[ni] = *reinterpret_cast<const bf16x8*>(&Bs[cur][bf_off + ni * 512]);
#pragma unroll
    for (int mi = 0; mi < 4; mi++)
#pragma unroll
      for (int ni = 0; ni < 4; ni++)
        acc[mi][ni] = __builtin_amdgcn_mfma_f32_16x16x32_bf16(af[mi], bfv[ni], acc[mi][ni], 0, 0, 0);
    __syncthreads();          // drains prefetch (latency covered by compute)
    cur ^= 1;
  }

  const int row0 = m0 + wr * 64 + l4 * 4;
  const int col0 = n0 + wc * 64 + l15;
  if constexpr (EPI == 1) {
    float* C = (float*)Cout;
#pragma unroll
    for (int mi = 0; mi < 4; mi++)
#pragma unroll
      for (int ni = 0; ni < 4; ni++)
#pragma unroll
        for (int j = 0; j < 4; j++)
          C[(size_t)(row0 + mi * 16 + j) * N + col0 + ni * 16] = acc[mi][ni][j];
  } else {
    if (n0 < QCOLS + KVCOLS) {
      // RoPE: acc[mi][ni][j] (d = ni*16+l15 < 32) pairs with acc[mi][ni+2][j] (d+32)
#pragma unroll
      for (int mi = 0; mi < 4; mi++)
#pragma unroll
        for (int j = 0; j < 4; j++) {
          int t = (row0 + mi * 16 + j) & (SEQ - 1);
#pragma unroll
          for (int ni = 0; ni < 2; ni++) {
            int d = ni * 16 + l15;
            float c = cosb[t * 32 + d], s = sinb[t * 32 + d];
            float a = acc[mi][ni][j], bb = acc[mi][ni + 2][j];
            acc[mi][ni][j]     = a * c - bb * s;
            acc[mi][ni + 2][j] = bb * c + a * s;
          }
        }
      if (n0 < QCOLS) {
        // Q: fold in softmax scale * log2(e) so k_attn uses exp2 directly
        const float QSC = 0.125f * 1.44269504088896f;
        u16* C = (u16*)Cout;  // Q bf16 [NQROWS][QCOLS], pre-scaled
#pragma unroll
        for (int mi = 0; mi < 4; mi++)
#pragma unroll
          for (int ni = 0; ni < 4; ni++)
#pragma unroll
            for (int j = 0; j < 4; j++)
              C[(size_t)(row0 + mi * 16 + j) * QCOLS + col0 + ni * 16] = f2bf(acc[mi][ni][j] * QSC);
      } else {
        int kc0 = col0 - QCOLS;
#pragma unroll
        for (int mi = 0; mi < 4; mi++)
#pragma unroll
          for (int ni = 0; ni < 4; ni++)
#pragma unroll
            for (int j = 0; j < 4; j++)
              dstK[(size_t)(row0 + mi * 16 + j) * KVCOLS + kc0 + ni * 16] = f2bf(acc[mi][ni][j]);
      }
    } else {
      // V^T: [B][KVCOLS][SEQ]
      int vc0 = col0 - (QCOLS + KVCOLS);
#pragma unroll
      for (int mi = 0; mi < 4; mi++) {
        int row = row0 + mi * 16;
        int b = row >> 11, t = row & (SEQ - 1);
#pragma unroll
        for (int ni = 0; ni < 4; ni++) {
          ushort4 v;
          v.x = f2bf(acc[mi][ni][0]);
          v.y = f2bf(acc[mi][ni][1]);
          v.z = f2bf(acc[mi][ni][2]);
          v.w = f2bf(acc[mi][ni][3]);
          *reinterpret_cast<ushort4*>(&dstV[((size_t)b * KVCOLS + vc0 + ni * 16) * SEQ + t]) = v;
        }
      }
    }
  }
}

// ---------------- causal GQA flash attention (adjacent dual-tile) --------
// grid (16, B*NH) = 1024 blocks, block 128 = 2 waves, wave owns 32 q-rows
// of ADJACENT tiles A=30-2*bxx, B=A+1 (same head -> SAME K/V chunks).
// vs R20's pairing (bxx,31-bxx) where only 136/392 iters were dual (A dies
// at kc>qtA), adjacent tiles share ALL chunks except B's final diag one ->
// ~100% dual iterations (272 dual, 0 solo): both independent QK->SM->PV
// chains live every iter, doubling intra-wave ILP over the whole loop.
// Imbalance (nkc=2..32) absorbed by longest-first order (bxx=0 -> 32 iters)
// at ~4 blocks/CU. Stage each chunk ONCE. XCD pinning kept (FETCH 12MB).
// Q pre-scaled in GEMM; P->A-frag via cvt_pk + permlane32_swap in regs.
__global__ __launch_bounds__(128, 2) void k_attn(const u16* __restrict__ Q,
                                                 const u16* __restrict__ K,
                                                 const u16* __restrict__ VT,
                                                 u16* __restrict__ AO) {
  __shared__ __align__(16) u16 Ks[2][4096];
  __shared__ __align__(16) u16 Vs[2][4096];
  const int tid = threadIdx.x;
  const int w = tid >> 6, l = tid & 63;
  const int lo = l & 31, hi = l >> 5;
  // XCD-pinned work remap (bijective on 1024 ids)
  const int id = blockIdx.y * gridDim.x + blockIdx.x;
  const int bh = (id & 7) * 8 + ((id >> 3) & 7);
  const int bxx = id >> 6;              // 0..15
  const int b = bh >> 5, h = bh & 31, g = h >> 2;
  const int srow = l >> 3, scol = l & 7;

  const u16* Kbase = K + ((size_t)b * SEQ) * KVCOLS + g * 64;
  const u16* Vbase = VT + ((size_t)(b * KVCOLS + g * 64)) * SEQ;

  const int qtA = 30 - 2 * bxx;     // even tile (longest-first: bxx=0 -> 30)
  const int qtB = qtA + 1;          // adjacent odd tile
  const int q0A = qtA * 64 + w * 32;
  const int q0B = qtB * 64 + w * 32;
  const int nkc = qtB + 1;
  const int qloc = w * 32 + lo;     // q within a 64-row tile (same for A,B)

  // Q B-frags for both tiles (col=lane&31=q, k=hi*8+e); pre-scaled
  bf16x8 qfA[4], qfB[4];
  {
    const u16* qpA = Q + (size_t)(b * SEQ + q0A + lo) * QCOLS + h * 64 + hi * 8;
    const u16* qpB = Q + (size_t)(b * SEQ + q0B + lo) * QCOLS + h * 64 + hi * 8;
#pragma unroll
    for (int kb = 0; kb < 4; kb++) {
      qfA[kb] = *reinterpret_cast<const bf16x8*>(qpA + kb * 16);
      qfB[kb] = *reinterpret_cast<const bf16x8*>(qpB + kb * 16);
    }
  }
  f32x16 oaccA[2] = {}, oaccB[2] = {};
  float lsA = 0.f, lsB = 0.f;

  // stage chunk 0 -> buf 0 (linear LDS dest, inverse-swizzled global col)
#pragma unroll
  for (int i = 0; i < 4; i++) {
    int r = w * 32 + i * 8 + srow;
    int cs = scol ^ (srow & 7);
    GLOAD16(Kbase + (size_t)r * KVCOLS + cs * 8, &Ks[0][(w * 32 + i * 8) * 64 + l * 8]);
    GLOAD16(Vbase + (size_t)r * SEQ + cs * 8, &Vs[0][(w * 32 + i * 8) * 64 + l * 8]);
  }
  __syncthreads();

  for (int kc = 0; kc < nkc; kc++) {
    const int bi = kc & 1;
    if (kc + 1 < nkc) {
#pragma unroll
      for (int i = 0; i < 4; i++) {
        int r = w * 32 + i * 8 + srow;
        int cs = scol ^ (srow & 7);
        GLOAD16(Kbase + (size_t)((kc + 1) * 64 + r) * KVCOLS + cs * 8,
                &Ks[bi ^ 1][(w * 32 + i * 8) * 64 + l * 8]);
        GLOAD16(Vbase + (size_t)r * SEQ + (kc + 1) * 64 + cs * 8,
                &Vs[bi ^ 1][(w * 32 + i * 8) * 64 + l * 8]);
      }
    }
    const bool doA = (kc <= qtA);
    u32 uA[2][4][2], uB[2][4][2];

    // ---- tile A: QK + softmax (sacc dies before B's is born) ----
    if (doA) {
      f32x16 saccA[2] = {};
      __builtin_amdgcn_s_setprio(1);
#pragma unroll
      for (int t = 0; t < 2; t++)
#pragma unroll
        for (int kb = 0; kb < 4; kb++) {
          int row = t * 32 + lo;
          int slot = (2 * kb + hi) ^ (lo & 7);
          bf16x8 kf = *reinterpret_cast<const bf16x8*>(&Ks[bi][row * 64 + slot * 8]);
          saccA[t] = __builtin_amdgcn_mfma_f32_32x32x16_bf16(kf, qfA[kb], saccA[t], 0, 0, 0);
        }
      __builtin_amdgcn_s_setprio(0);
      const bool diagA = (kc == qtA);
#pragma unroll
      for (int t = 0; t < 2; t++) {
        float pv[16];
#pragma unroll
        for (int r = 0; r < 16; r++) {
          float e = exp2f(saccA[t][r]);
          if (diagA) {
            int kvoff = t * 32 + (r & 3) + 8 * (r >> 2) + 4 * hi;
            if (kvoff > qloc) e = 0.f;
          }
          pv[r] = e; lsA += e;
        }
#pragma unroll
        for (int qd = 0; qd < 4; qd++)
#pragma unroll
          for (int hh = 0; hh < 2; hh++) {
            u32 uu;
            asm("v_cvt_pk_bf16_f32 %0, %1, %2"
                : "=v"(uu) : "v"(pv[qd * 4 + 2 * hh]), "v"(pv[qd * 4 + 2 * hh + 1]));
            uA[t][qd][hh] = uu;
          }
      }
    }

    // ---- tile B: QK + softmax ----
    {
      f32x16 saccB[2] = {};
      __builtin_amdgcn_s_setprio(1);
#pragma unroll
      for (int t = 0; t < 2; t++)
#pragma unroll
        for (int kb = 0; kb < 4; kb++) {
          int row = t * 32 + lo;
          int slot = (2 * kb + hi) ^ (lo & 7);
          bf16x8 kf = *reinterpret_cast<const bf16x8*>(&Ks[bi][row * 64 + slot * 8]);
          saccB[t] = __builtin_amdgcn_mfma_f32_32x32x16_bf16(kf, qfB[kb], saccB[t], 0, 0, 0);
        }
      __builtin_amdgcn_s_setprio(0);
      const bool diagB = (kc == qtB);
#pragma unroll
      for (int t = 0; t < 2; t++) {
        float pv[16];
#pragma unroll
        for (int r = 0; r < 16; r++) {
          float e = exp2f(saccB[t][r]);
          if (diagB) {
            int kvoff = t * 32 + (r & 3) + 8 * (r >> 2) + 4 * hi;
            if (kvoff > qloc) e = 0.f;
          }
          pv[r] = e; lsB += e;
        }
#pragma unroll
        for (int qd = 0; qd < 4; qd++)
#pragma unroll
          for (int hh = 0; hh < 2; hh++) {
            u32 uu;
            asm("v_cvt_pk_bf16_f32 %0, %1, %2"
                : "=v"(uu) : "v"(pv[qd * 4 + 2 * hh]), "v"(pv[qd * 4 + 2 * hh + 1]));
            uB[t][qd][hh] = uu;
          }
      }
    }

    // ---- PV for A then B (independent chains; scheduler interleaves) ----
    if (doA) {
#pragma unroll
      for (int km = 0; km < 4; km++) {
        const int t = km >> 1, p = km & 1;
        u32 a0 = uA[t][2 * p][0], b0 = uA[t][2 * p + 1][0];
        u32 a1 = uA[t][2 * p][1], b1 = uA[t][2 * p + 1][1];
        asm("v_permlane32_swap_b32 %0, %1" : "+v"(a0), "+v"(b0));
        asm("v_permlane32_swap_b32 %0, %1" : "+v"(a1), "+v"(b1));
        union { u32 uu[4]; bf16x8 v; } pa;
        pa.uu[0] = a0; pa.uu[1] = a1; pa.uu[2] = b0; pa.uu[3] = b1;
        __builtin_amdgcn_s_setprio(1);
#pragma unroll
        for (int td = 0; td < 2; td++) {
          int row = td * 32 + lo;
          int slot = (2 * km + hi) ^ (lo & 7);
          bf16x8 vf = *reinterpret_cast<const bf16x8*>(&Vs[bi][row * 64 + slot * 8]);
          oaccA[td] = __builtin_amdgcn_mfma_f32_32x32x16_bf16(pa.v, vf, oaccA[td], 0, 0, 0);
        }
        __builtin_amdgcn_s_setprio(0);
      }
    }
#pragma unroll
    for (int km = 0; km < 4; km++) {
      const int t = km >> 1, p = km & 1;
      u32 a0 = uB[t][2 * p][0], b0 = uB[t][2 * p + 1][0];
      u32 a1 = uB[t][2 * p][1], b1 = uB[t][2 * p + 1][1];
      asm("v_permlane32_swap_b32 %0, %1" : "+v"(a0), "+v"(b0));
      asm("v_permlane32_swap_b32 %0, %1" : "+v"(a1), "+v"(b1));
      union { u32 uu[4]; bf16x8 v; } pa;
      pa.uu[0] = a0; pa.uu[1] = a1; pa.uu[2] = b0; pa.uu[3] = b1;
      __builtin_amdgcn_s_setprio(1);
#pragma unroll
      for (int td = 0; td < 2; td++) {
        int row = td * 32 + lo;
        int slot = (2 * km + hi) ^ (lo & 7);
        bf16x8 vf = *reinterpret_cast<const bf16x8*>(&Vs[bi][row * 64 + slot * 8]);
        oaccB[td] = __builtin_amdgcn_mfma_f32_32x32x16_bf16(pa.v, vf, oaccB[td], 0, 0, 0);
      }
      __builtin_amdgcn_s_setprio(0);
    }
    __syncthreads();
  }

  // epilogues: per-tile denom broadcast + normalize + store
  {
    float tot = lsA;
    tot += __shfl_xor(tot, 32);
#pragma unroll
    for (int r = 0; r < 16; r++) {
      int qr = (r & 3) + 8 * (r >> 2) + 4 * hi;
      float den = __shfl(tot, qr);
      float rv = __builtin_amdgcn_rcpf(den);
      size_t rowbase = (size_t)(b * SEQ + q0A + qr) * QCOLS + h * 64 + lo;
      AO[rowbase]      = f2bf(oaccA[0][r] * rv);
      AO[rowbase + 32] = f2bf(oaccA[1][r] * rv);
    }
  }
  {
    float tot = lsB;
    tot += __shfl_xor(tot, 32);
#pragma unroll
    for (int r = 0; r < 16; r++) {
      int qr = (r & 3) + 8 * (r >> 2) + 4 * hi;
      float den = __shfl(tot, qr);
      float rv = __builtin_amdgcn_rcpf(den);
      size_t rowbase = (size_t)(b * SEQ + q0B + qr) * QCOLS + h * 64 + lo;
      AO[rowbase]      = f2bf(oaccB[0][r] * rv);
      AO[rowbase + 32] = f2bf(oaccB[1][r] * rv);
    }
  }
}

extern "C" void kernel_launch(void* const* d_in, const int* in_sizes, int n_in,
                              void* d_out, int out_size, void* d_ws, size_t ws_size,
                              hipStream_t stream) {
  const float* x    = (const float*)d_in[0];
  const float* cosb = (const float*)d_in[1];
  const float* sinb = (const float*)d_in[2];
  const float* wq   = (const float*)d_in[3];
  const float* wk   = (const float*)d_in[4];
  const float* wv   = (const float*)d_in[5];
  const float* wo   = (const float*)d_in[6];
  float* out = (float*)d_out;

  char* ws = (char*)d_ws;
  size_t off = 0;
  auto alloc = [&](size_t bytes) -> void* {
    void* p = ws + off;
    off += (bytes + 255) & ~(size_t)255;
    return p;
  };
  u16* xb    = (u16*)alloc((size_t)NQROWS * DMODEL * 2);
  u16* wcatT = (u16*)alloc((size_t)NCAT * DMODEL * 2);     // [wq|wk|wv]^T
  u16* woT   = (u16*)alloc((size_t)DMODEL * QCOLS * 2);
  u16* Qb    = (u16*)alloc((size_t)NQROWS * QCOLS * 2);
  u16* Kb    = (u16*)alloc((size_t)NQROWS * KVCOLS * 2);
  u16* VTb   = (u16*)alloc((size_t)BATCH * KVCOLS * SEQ * 2);
  u16* AO    = (u16*)alloc((size_t)NQROWS * QCOLS * 2);

  k_cvt_bf16<<<dim3(NQROWS * DMODEL / 4 / 256), dim3(256), 0, stream>>>(x, xb, NQROWS * DMODEL / 4);
  k_transpose_all<<<dim3(10240), dim3(256), 0, stream>>>(wq, wk, wv, wo, wcatT, woT);

  // fused QKV projection + RoPE epilogue (Q->Qb prescaled, K->Kb, V->VT)
  k_gemm<3><<<dim3(NCAT / 128, NQROWS / 128), 256, 0, stream>>>(
      xb, wcatT, Qb, NQROWS, NCAT, DMODEL, cosb, sinb, Kb, VTb);

  // attention (adjacent dual-tile, XCD-pinned)
  k_attn<<<dim3(16, BATCH * NH), 128, 0, stream>>>(Qb, Kb, VTb, AO);

  // output projection -> f32
  k_gemm<1><<<dim3(DMODEL / 128, NQROWS / 128), 256, 0, stream>>>(
      AO, woT, out, NQROWS, DMODEL, QCOLS, nullptr, nullptr, nullptr, nullptr);
}

// Round 22
// 215.822 us; speedup vs baseline: 1.0442x; 1.0442x over previous
//
#include <hip/hip_runtime.h>
#include <hip/hip_bf16.h>
#include <cstdint>

typedef unsigned short u16;
typedef unsigned int u32;
typedef __bf16 bf16x8 __attribute__((ext_vector_type(8)));
typedef float f32x4 __attribute__((ext_vector_type(4)));
typedef float f32x16 __attribute__((ext_vector_type(16)));

#define BATCH 2
#define SEQ 2048
#define DMODEL 2048
#define NH 32
#define NKVH 8
#define HD 64
#define NQROWS (BATCH*SEQ)   // 4096
#define QCOLS (NH*HD)        // 2048
#define KVCOLS (NKVH*HD)     // 512
#define NCAT (QCOLS+2*KVCOLS) // 3072

static __device__ __forceinline__ u16 f2bf(float f) {
  u32 u = __float_as_uint(f);
  return (u16)((u + 0x7fffu + ((u >> 16) & 1u)) >> 16);   // RNE
}

// async global->LDS, 16B per lane, wave-uniform LDS base + lane*16
#define GLOAD16(gp, lp) __builtin_amdgcn_global_load_lds( \
    (const __attribute__((address_space(1))) void*)(gp),  \
    (__attribute__((address_space(3))) void*)(lp), 16, 0, 0)

// ---------------- f32 -> bf16 convert ----------------
__global__ __launch_bounds__(256) void k_cvt_bf16(const float* __restrict__ in,
                                                  u16* __restrict__ out, int n4) {
  int i = blockIdx.x * 256 + threadIdx.x;
  if (i >= n4) return;
  float4 v = reinterpret_cast<const float4*>(in)[i];
  ushort4 o;
  o.x = f2bf(v.x); o.y = f2bf(v.y); o.z = f2bf(v.z); o.w = f2bf(v.w);
  reinterpret_cast<ushort4*>(out)[i] = o;
}

// ------- merged weight transposes: one launch for wq|wk|wv -> wcatT, wo -> woT
__global__ __launch_bounds__(256) void k_transpose_all(const float* __restrict__ wq,
                                                       const float* __restrict__ wk,
                                                       const float* __restrict__ wv,
                                                       const float* __restrict__ wo,
                                                       u16* __restrict__ wcatT,
                                                       u16* __restrict__ woT) {
  __shared__ float tile[32][33];
  const int tidx = blockIdx.x;
  const float* src; u16* dst; int C, c0, r0;
  if (tidx < 4096) {
    src = wq; dst = wcatT; C = QCOLS;
    c0 = (tidx & 63) * 32; r0 = (tidx >> 6) * 32;
  } else if (tidx < 5120) {
    int t2 = tidx - 4096;
    src = wk; dst = wcatT + (size_t)QCOLS * DMODEL; C = KVCOLS;
    c0 = (t2 & 15) * 32; r0 = (t2 >> 4) * 32;
  } else if (tidx < 6144) {
    int t2 = tidx - 5120;
    src = wv; dst = wcatT + (size_t)(QCOLS + KVCOLS) * DMODEL; C = KVCOLS;
    c0 = (t2 & 15) * 32; r0 = (t2 >> 4) * 32;
  } else {
    int t2 = tidx - 6144;
    src = wo; dst = woT; C = DMODEL;
    c0 = (t2 & 63) * 32; r0 = (t2 >> 6) * 32;
  }
  const int R = 2048;  // all sources have 2048 rows
  int tx = threadIdx.x & 31, ty = threadIdx.x >> 5;  // 32 x 8
#pragma unroll
  for (int i = 0; i < 4; i++)
    tile[ty * 4 + i][tx] = src[(size_t)(r0 + ty * 4 + i) * C + c0 + tx];
  __syncthreads();
#pragma unroll
  for (int i = 0; i < 4; i++)
    dst[(size_t)(c0 + ty * 4 + i) * R + r0 + tx] = f2bf(tile[tx][ty * 4 + i]);
}

// ---------------- bf16 GEMM: C[M][N] = A[M][K] * BT[N][K]^T ----------------
// 128x128 tile, BK=32, 4 waves each owning 64x64 (4x4 frags).
// 2-PHASE DBUF + XCD swizzle. EPI 1: f32 out. EPI 3: fused QKV epilogue.
template<int EPI>
__global__ __launch_bounds__(256) void k_gemm(const u16* __restrict__ A,
                                              const u16* __restrict__ BT,
                                              void* __restrict__ Cout,
                                              int M, int N, int K,
                                              const float* __restrict__ cosb,
                                              const float* __restrict__ sinb,
                                              u16* __restrict__ dstK,
                                              u16* __restrict__ dstV) {
  __shared__ __align__(16) u16 As[2][128 * 32];
  __shared__ __align__(16) u16 Bs[2][128 * 32];
  const int tid = threadIdx.x;
  const int w = tid >> 6, l = tid & 63;
  const int l15 = l & 15, l4 = l >> 4;

  const int nwg = gridDim.x * gridDim.y;
  int hwid = blockIdx.y * gridDim.x + blockIdx.x;
  int wk = (hwid & 7) * (nwg >> 3) + (hwid >> 3);
  const int bx = wk % gridDim.x, by = wk / gridDim.x;

  const int m0 = by * 128, n0 = bx * 128;
  const int wr = w >> 1, wc = w & 1;

  const u16* ga = A + (size_t)(m0 + w * 32 + (l >> 2)) * K + (l & 3) * 8;
  const u16* gb = BT + (size_t)(n0 + w * 32 + (l >> 2)) * K + (l & 3) * 8;
  const int af_off = (wr * 64 + l15) * 32 + l4 * 8;
  const int bf_off = (wc * 64 + l15) * 32 + l4 * 8;

  auto stage = [&](int buf, int kt) {
    const u16* ga_ = ga + kt;
    const u16* gb_ = gb + kt;
    u16* asb = &As[buf][w * 1024];
    u16* bsb = &Bs[buf][w * 1024];
    GLOAD16(ga_, asb);
    GLOAD16(ga_ + 16 * (size_t)K, asb + 512);
    GLOAD16(gb_, bsb);
    GLOAD16(gb_ + 16 * (size_t)K, bsb + 512);
  };

  f32x4 acc[4][4] = {};
  stage(0, 0);
  __syncthreads();

  int cur = 0;
  for (int kt = 0; kt < K; kt += 32) {
    if (kt + 32 < K) stage(cur ^ 1, kt + 32);
    bf16x8 af[4], bfv[4];
#pragma unroll
    for (int mi = 0; mi < 4; mi++)
      af[mi] = *reinterpret_cast<const bf16x8*>(&As[cur][af_off + mi * 512]);
#pragma unroll
    for (int ni = 0; ni < 4; ni++)
      bfv[ni] = *reinterpret_cast<const bf16x8*>(&Bs[cur][bf_off + ni * 512]);
#pragma unroll
    for (int mi = 0; mi < 4; mi++)
#pragma unroll
      for (int ni = 0; ni < 4; ni++)
        acc[mi][ni] = __builtin_amdgcn_mfma_f32_16x16x32_bf16(af[mi], bfv[ni], acc[mi][ni], 0, 0, 0);
    __syncthreads();
    cur ^= 1;
  }

  const int row0 = m0 + wr * 64 + l4 * 4;
  const int col0 = n0 + wc * 64 + l15;
  if constexpr (EPI == 1) {
    float* C = (float*)Cout;
#pragma unroll
    for (int mi = 0; mi < 4; mi++)
#pragma unroll
      for (int ni = 0; ni < 4; ni++)
#pragma unroll
        for (int j = 0; j < 4; j++)
          C[(size_t)(row0 + mi * 16 + j) * N + col0 + ni * 16] = acc[mi][ni][j];
  } else {
    if (n0 < QCOLS + KVCOLS) {
#pragma unroll
      for (int mi = 0; mi < 4; mi++)
#pragma unroll
        for (int j = 0; j < 4; j++) {
          int t = (row0 + mi * 16 + j) & (SEQ - 1);
#pragma unroll
          for (int ni = 0; ni < 2; ni++) {
            int d = ni * 16 + l15;
            float c = cosb[t * 32 + d], s = sinb[t * 32 + d];
            float a = acc[mi][ni][j], bb = acc[mi][ni + 2][j];
            acc[mi][ni][j]     = a * c - bb * s;
            acc[mi][ni + 2][j] = bb * c + a * s;
          }
        }
      if (n0 < QCOLS) {
        const float QSC = 0.125f * 1.44269504088896f;
        u16* C = (u16*)Cout;  // Q bf16, pre-scaled
#pragma unroll
        for (int mi = 0; mi < 4; mi++)
#pragma unroll
          for (int ni = 0; ni < 4; ni++)
#pragma unroll
            for (int j = 0; j < 4; j++)
              C[(size_t)(row0 + mi * 16 + j) * QCOLS + col0 + ni * 16] = f2bf(acc[mi][ni][j] * QSC);
      } else {
        int kc0 = col0 - QCOLS;
#pragma unroll
        for (int mi = 0; mi < 4; mi++)
#pragma unroll
          for (int ni = 0; ni < 4; ni++)
#pragma unroll
            for (int j = 0; j < 4; j++)
              dstK[(size_t)(row0 + mi * 16 + j) * KVCOLS + kc0 + ni * 16] = f2bf(acc[mi][ni][j]);
      }
    } else {
      int vc0 = col0 - (QCOLS + KVCOLS);
#pragma unroll
      for (int mi = 0; mi < 4; mi++) {
        int row = row0 + mi * 16;
        int b = row >> 11, t = row & (SEQ - 1);
#pragma unroll
        for (int ni = 0; ni < 4; ni++) {
          ushort4 v;
          v.x = f2bf(acc[mi][ni][0]);
          v.y = f2bf(acc[mi][ni][1]);
          v.z = f2bf(acc[mi][ni][2]);
          v.w = f2bf(acc[mi][ni][3]);
          *reinterpret_cast<ushort4*>(&dstV[((size_t)b * KVCOLS + vc0 + ni * 16) * SEQ + t]) = v;
        }
      }
    }
  }
}

// ------- causal GQA flash attention (balanced always-dual chains) --------
// grid (16, B*NH) = 1024 blocks, block 128 = 2 waves, wave owns 32 q-rows
// of pair {A=bxx, B=31-bxx} (compute-balanced: 66 32-row chunks/pair).
// The pair's chunk list is SPLIT EVENLY across two always-active chains
// (33 items each): chain1 = A's 2bxx+2 chunks then B's 0..30-2bxx;
// chain2 = B's 31-2bxx..63-2bxx. 100% dual iterations + uniform 33-iter
// blocks (R20 was 35% dual; R21's adjacent pairing was 20x imbalanced).
// Fixed-shift softmax makes the KV split mergeable: oaccB/lsB accumulate
// from both chains (same-acc MFMAs chain at full rate; ILP needed is
// VALU/TRANS vs MFMA, preserved). Chunk=32 rows: 2 streams x dbuf x 8KB
// = 32KB LDS. XCD pinning kept. Q pre-scaled in GEMM.
__global__ __launch_bounds__(128, 2) void k_attn(const u16* __restrict__ Q,
                                                 const u16* __restrict__ K,
                                                 const u16* __restrict__ VT,
                                                 u16* __restrict__ AO) {
  __shared__ __align__(16) u16 Ks[2][2][2048];   // [stream][dbuf][32kv x 64d]
  __shared__ __align__(16) u16 Vs[2][2][2048];   // [stream][dbuf][64d x 32kv]
  const int tid = threadIdx.x;
  const int w = tid >> 6, l = tid & 63;
  const int lo = l & 31, hi = l >> 5;
  // XCD-pinned work remap (bijective on 1024 ids)
  const int id = blockIdx.y * gridDim.x + blockIdx.x;
  const int bh = (id & 7) * 8 + ((id >> 3) & 7);
  const int bxx = id >> 6;              // 0..15
  const int b = bh >> 5, h = bh & 31, g = h >> 2;

  const u16* Kbase = K + ((size_t)b * SEQ) * KVCOLS + g * 64;
  const u16* Vbase = VT + ((size_t)(b * KVCOLS + g * 64)) * SEQ;

  const int qtA = bxx, qtB = 31 - bxx;
  const int q0A = qtA * 64 + w * 32;
  const int q0B = qtB * 64 + w * 32;
  const int nA = 2 * bxx + 2;       // chain1's A-chunk count
  const int c2base = 33 - nA;       // chain2's first B-chunk

  // K staging lane mapping (32 rows x 64 d)
  const int k_r = l >> 3, k_cs = (l & 7) ^ (l >> 3);
  // V staging lane mapping (64 d-rows x 32 kv)
  const int v_r = l >> 2, v_cs = (l & 3) ^ ((l >> 2) & 3);

  auto stage = [&](int s, int bi, int c) {
#pragma unroll
    for (int i = 0; i < 2; i++) {
      GLOAD16(Kbase + (size_t)(c * 32 + w * 16 + i * 8 + k_r) * KVCOLS + k_cs * 8,
              &Ks[s][bi][(w * 16 + i * 8) * 64 + l * 8]);
      GLOAD16(Vbase + (size_t)(w * 32 + i * 16 + v_r) * SEQ + c * 32 + v_cs * 8,
              &Vs[s][bi][(w * 32 + i * 16) * 32 + l * 8]);
    }
  };
  auto c1_of = [&](int j) { return j < nA ? j : j - nA; };

  // Q B-frags for both tiles (pre-scaled by 0.125*log2e in GEMM)
  bf16x8 qfA[4], qfB[4];
  {
    const u16* qpA = Q + (size_t)(b * SEQ + q0A + lo) * QCOLS + h * 64 + hi * 8;
    const u16* qpB = Q + (size_t)(b * SEQ + q0B + lo) * QCOLS + h * 64 + hi * 8;
#pragma unroll
    for (int kb = 0; kb < 4; kb++) {
      qfA[kb] = *reinterpret_cast<const bf16x8*>(qpA + kb * 16);
      qfB[kb] = *reinterpret_cast<const bf16x8*>(qpB + kb * 16);
    }
  }
  f32x16 oaccA[2] = {}, oaccB[2] = {};
  float lsA = 0.f, lsB = 0.f;

  // one chain's compute step: 32kv x 32q QK -> softmax -> PV into oacc
  auto chain = [&](int s, int bi, int c, const bf16x8* qf, f32x16* oacc,
                   float& ls, int qt, int q0) {
    f32x16 sacc = {};
    __builtin_amdgcn_s_setprio(1);
#pragma unroll
    for (int kb = 0; kb < 4; kb++) {
      int slot = (2 * kb + hi) ^ (lo & 7);
      bf16x8 kf = *reinterpret_cast<const bf16x8*>(&Ks[s][bi][lo * 64 + slot * 8]);
      sacc = __builtin_amdgcn_mfma_f32_32x32x16_bf16(kf, qf[kb], sacc, 0, 0, 0);
    }
    __builtin_amdgcn_s_setprio(0);
    const bool msk = (c >= 2 * qt);   // uniform: diag or beyond
    float pv[16];
#pragma unroll
    for (int r = 0; r < 16; r++) {
      float e = exp2f(sacc[r]);
      if (msk) {
        int kvg = c * 32 + (r & 3) + 8 * (r >> 2) + 4 * hi;
        if (kvg > q0 + lo) e = 0.f;
      }
      pv[r] = e; ls += e;
    }
    u32 u[4][2];
#pragma unroll
    for (int qd = 0; qd < 4; qd++)
#pragma unroll
      for (int hh = 0; hh < 2; hh++) {
        u32 uu;
        asm("v_cvt_pk_bf16_f32 %0, %1, %2"
            : "=v"(uu) : "v"(pv[qd * 4 + 2 * hh]), "v"(pv[qd * 4 + 2 * hh + 1]));
        u[qd][hh] = uu;
      }
#pragma unroll
    for (int km = 0; km < 2; km++) {
      u32 a0 = u[2 * km][0], b0 = u[2 * km + 1][0];
      u32 a1 = u[2 * km][1], b1 = u[2 * km + 1][1];
      asm("v_permlane32_swap_b32 %0, %1" : "+v"(a0), "+v"(b0));
      asm("v_permlane32_swap_b32 %0, %1" : "+v"(a1), "+v"(b1));
      union { u32 uu[4]; bf16x8 v; } pa;
      pa.uu[0] = a0; pa.uu[1] = a1; pa.uu[2] = b0; pa.uu[3] = b1;
      __builtin_amdgcn_s_setprio(1);
#pragma unroll
      for (int td = 0; td < 2; td++) {
        int row = td * 32 + lo;
        int slot = (2 * km + hi) ^ (row & 3);
        bf16x8 vf = *reinterpret_cast<const bf16x8*>(&Vs[s][bi][row * 32 + slot * 8]);
        oacc[td] = __builtin_amdgcn_mfma_f32_32x32x16_bf16(pa.v, vf, oacc[td], 0, 0, 0);
      }
      __builtin_amdgcn_s_setprio(0);
    }
  };

  // prologue: both streams' item 0
  stage(0, 0, c1_of(0));
  stage(1, 0, c2base);
  __syncthreads();

  for (int j = 0; j < 33; j++) {
    const int bi = j & 1;
    if (j + 1 < 33) {
      stage(0, bi ^ 1, c1_of(j + 1));
      stage(1, bi ^ 1, c2base + j + 1);
    }
    // chain1: tile A while j < nA, else tile B
    if (j < nA) chain(0, bi, j, qfA, oaccA, lsA, qtA, q0A);
    else        chain(0, bi, j - nA, qfB, oaccB, lsB, qtB, q0B);
    // chain2: always tile B
    chain(1, bi, c2base + j, qfB, oaccB, lsB, qtB, q0B);
    __syncthreads();
  }

  // epilogues: per-tile denom broadcast + normalize + store
  {
    float tot = lsA;
    tot += __shfl_xor(tot, 32);
#pragma unroll
    for (int r = 0; r < 16; r++) {
      int qr = (r & 3) + 8 * (r >> 2) + 4 * hi;
      float den = __shfl(tot, qr);
      float rv = __builtin_amdgcn_rcpf(den);
      size_t rowbase = (size_t)(b * SEQ + q0A + qr) * QCOLS + h * 64 + lo;
      AO[rowbase]      = f2bf(oaccA[0][r] * rv);
      AO[rowbase + 32] = f2bf(oaccA[1][r] * rv);
    }
  }
  {
    float tot = lsB;
    tot += __shfl_xor(tot, 32);
#pragma unroll
    for (int r = 0; r < 16; r++) {
      int qr = (r & 3) + 8 * (r >> 2) + 4 * hi;
      float den = __shfl(tot, qr);
      float rv = __builtin_amdgcn_rcpf(den);
      size_t rowbase = (size_t)(b * SEQ + q0B + qr) * QCOLS + h * 64 + lo;
      AO[rowbase]      = f2bf(oaccB[0][r] * rv);
      AO[rowbase + 32] = f2bf(oaccB[1][r] * rv);
    }
  }
}

extern "C" void kernel_launch(void* const* d_in, const int* in_sizes, int n_in,
                              void* d_out, int out_size, void* d_ws, size_t ws_size,
                              hipStream_t stream) {
  const float* x    = (const float*)d_in[0];
  const float* cosb = (const float*)d_in[1];
  const float* sinb = (const float*)d_in[2];
  const float* wq   = (const float*)d_in[3];
  const float* wk   = (const float*)d_in[4];
  const float* wv   = (const float*)d_in[5];
  const float* wo   = (const float*)d_in[6];
  float* out = (float*)d_out;

  char* ws = (char*)d_ws;
  size_t off = 0;
  auto alloc = [&](size_t bytes) -> void* {
    void* p = ws + off;
    off += (bytes + 255) & ~(size_t)255;
    return p;
  };
  u16* xb    = (u16*)alloc((size_t)NQROWS * DMODEL * 2);
  u16* wcatT = (u16*)alloc((size_t)NCAT * DMODEL * 2);     // [wq|wk|wv]^T
  u16* woT   = (u16*)alloc((size_t)DMODEL * QCOLS * 2);
  u16* Qb    = (u16*)alloc((size_t)NQROWS * QCOLS * 2);
  u16* Kb    = (u16*)alloc((size_t)NQROWS * KVCOLS * 2);
  u16* VTb   = (u16*)alloc((size_t)BATCH * KVCOLS * SEQ * 2);
  u16* AO    = (u16*)alloc((size_t)NQROWS * QCOLS * 2);

  k_cvt_bf16<<<dim3(NQROWS * DMODEL / 4 / 256), dim3(256), 0, stream>>>(x, xb, NQROWS * DMODEL / 4);
  k_transpose_all<<<dim3(10240), dim3(256), 0, stream>>>(wq, wk, wv, wo, wcatT, woT);

  // fused QKV projection + RoPE epilogue (Q->Qb prescaled, K->Kb, V->VT)
  k_gemm<3><<<dim3(NCAT / 128, NQROWS / 128), 256, 0, stream>>>(
      xb, wcatT, Qb, NQROWS, NCAT, DMODEL, cosb, sinb, Kb, VTb);

  // attention (balanced always-dual chains, XCD-pinned)
  k_attn<<<dim3(16, BATCH * NH), 128, 0, stream>>>(Qb, Kb, VTb, AO);

  // output projection -> f32
  k_gemm<1><<<dim3(DMODEL / 128, NQROWS / 128), 256, 0, stream>>>(
      AO, woT, out, NQROWS, DMODEL, QCOLS, nullptr, nullptr, nullptr, nullptr);
}

// Round 23
// 199.690 us; speedup vs baseline: 1.1286x; 1.0808x over previous
//
#include <hip/hip_runtime.h>
#include <hip/hip_bf16.h>
#include <cstdint>

typedef unsigned short u16;
typedef unsigned int u32;
typedef __bf16 bf16x8 __attribute__((ext_vector_type(8)));
typedef float f32x4 __attribute__((ext_vector_type(4)));
typedef float f32x16 __attribute__((ext_vector_type(16)));

#define BATCH 2
#define SEQ 2048
#define DMODEL 2048
#define NH 32
#define NKVH 8
#define HD 64
#define NQROWS (BATCH*SEQ)   // 4096
#define QCOLS (NH*HD)        // 2048
#define KVCOLS (NKVH*HD)     // 512
#define NCAT (QCOLS+2*KVCOLS) // 3072

static __device__ __forceinline__ u16 f2bf(float f) {
  u32 u = __float_as_uint(f);
  return (u16)((u + 0x7fffu + ((u >> 16) & 1u)) >> 16);   // RNE
}

// async global->LDS, 16B per lane, wave-uniform LDS base + lane*16
#define GLOAD16(gp, lp) __builtin_amdgcn_global_load_lds( \
    (const __attribute__((address_space(1))) void*)(gp),  \
    (__attribute__((address_space(3))) void*)(lp), 16, 0, 0)

// ------- merged prep: weight transposes (blocks 0..10239) + x f32->bf16
// convert (blocks 10240..18431). All independent; one launch.
__global__ __launch_bounds__(256) void k_prep(const float* __restrict__ wq,
                                              const float* __restrict__ wk,
                                              const float* __restrict__ wv,
                                              const float* __restrict__ wo,
                                              const float* __restrict__ x,
                                              u16* __restrict__ wcatT,
                                              u16* __restrict__ woT,
                                              u16* __restrict__ xb) {
  const int tidx = blockIdx.x;
  if (tidx >= 10240) {
    int i = (tidx - 10240) * 256 + threadIdx.x;  // 8192 blocks x 256 = 2M f32x4
    float4 v = reinterpret_cast<const float4*>(x)[i];
    ushort4 o;
    o.x = f2bf(v.x); o.y = f2bf(v.y); o.z = f2bf(v.z); o.w = f2bf(v.w);
    reinterpret_cast<ushort4*>(xb)[i] = o;
    return;
  }
  __shared__ float tile[32][33];
  const float* src; u16* dst; int C, c0, r0;
  if (tidx < 4096) {
    src = wq; dst = wcatT; C = QCOLS;
    c0 = (tidx & 63) * 32; r0 = (tidx >> 6) * 32;
  } else if (tidx < 5120) {
    int t2 = tidx - 4096;
    src = wk; dst = wcatT + (size_t)QCOLS * DMODEL; C = KVCOLS;
    c0 = (t2 & 15) * 32; r0 = (t2 >> 4) * 32;
  } else if (tidx < 6144) {
    int t2 = tidx - 5120;
    src = wv; dst = wcatT + (size_t)(QCOLS + KVCOLS) * DMODEL; C = KVCOLS;
    c0 = (t2 & 15) * 32; r0 = (t2 >> 4) * 32;
  } else {
    int t2 = tidx - 6144;
    src = wo; dst = woT; C = DMODEL;
    c0 = (t2 & 63) * 32; r0 = (t2 >> 6) * 32;
  }
  const int R = 2048;  // all sources have 2048 rows
  int tx = threadIdx.x & 31, ty = threadIdx.x >> 5;  // 32 x 8
#pragma unroll
  for (int i = 0; i < 4; i++)
    tile[ty * 4 + i][tx] = src[(size_t)(r0 + ty * 4 + i) * C + c0 + tx];
  __syncthreads();
#pragma unroll
  for (int i = 0; i < 4; i++)
    dst[(size_t)(c0 + ty * 4 + i) * R + r0 + tx] = f2bf(tile[tx][ty * 4 + i]);
}

// ---------------- bf16 GEMM: C[M][N] = A[M][K] * BT[N][K]^T ----------------
// 128x128 tile, BK=32, 4 waves each owning 64x64 (4x4 frags).
// 2-PHASE DBUF: stage(next K-tile) issued BEFORE current tile's compute;
// ONE __syncthreads per K-step. XCD-aware bijective block swizzle.
// EPI 1: f32 out.  EPI 3: fused QKV epilogue (Q RoPE+scale, K RoPE, V^T).
template<int EPI>
__global__ __launch_bounds__(256) void k_gemm(const u16* __restrict__ A,
                                              const u16* __restrict__ BT,
                                              void* __restrict__ Cout,
                                              int M, int N, int K,
                                              const float* __restrict__ cosb,
                                              const float* __restrict__ sinb,
                                              u16* __restrict__ dstK,
                                              u16* __restrict__ dstV) {
  __shared__ __align__(16) u16 As[2][128 * 32];
  __shared__ __align__(16) u16 Bs[2][128 * 32];
  const int tid = threadIdx.x;
  const int w = tid >> 6, l = tid & 63;
  const int l15 = l & 15, l4 = l >> 4;

  // XCD swizzle: hw id -> contiguous work chunk per XCD (nwg % 8 == 0)
  const int nwg = gridDim.x * gridDim.y;
  int hwid = blockIdx.y * gridDim.x + blockIdx.x;
  int wk = (hwid & 7) * (nwg >> 3) + (hwid >> 3);
  const int bx = wk % gridDim.x, by = wk / gridDim.x;

  const int m0 = by * 128, n0 = bx * 128;
  const int wr = w >> 1, wc = w & 1;

  const u16* ga = A + (size_t)(m0 + w * 32 + (l >> 2)) * K + (l & 3) * 8;
  const u16* gb = BT + (size_t)(n0 + w * 32 + (l >> 2)) * K + (l & 3) * 8;
  const int af_off = (wr * 64 + l15) * 32 + l4 * 8;
  const int bf_off = (wc * 64 + l15) * 32 + l4 * 8;

  auto stage = [&](int buf, int kt) {
    const u16* ga_ = ga + kt;
    const u16* gb_ = gb + kt;
    u16* asb = &As[buf][w * 1024];
    u16* bsb = &Bs[buf][w * 1024];
    GLOAD16(ga_, asb);
    GLOAD16(ga_ + 16 * (size_t)K, asb + 512);
    GLOAD16(gb_, bsb);
    GLOAD16(gb_ + 16 * (size_t)K, bsb + 512);
  };

  f32x4 acc[4][4] = {};
  stage(0, 0);
  __syncthreads();            // prologue: tile 0 resident

  int cur = 0;
  for (int kt = 0; kt < K; kt += 32) {
    if (kt + 32 < K) stage(cur ^ 1, kt + 32);   // prefetch next tile (async)
    bf16x8 af[4], bfv[4];
#pragma unroll
    for (int mi = 0; mi < 4; mi++)
      af[mi] = *reinterpret_cast<const bf16x8*>(&As[cur][af_off + mi * 512]);
#pragma unroll
    for (int ni = 0; ni < 4; ni++)
      bfv[ni] = *reinterpret_cast<const bf16x8*>(&Bs[cur][bf_off + ni * 512]);
#pragma unroll
    for (int mi = 0; mi < 4; mi++)
#pragma unroll
      for (int ni = 0; ni < 4; ni++)
        acc[mi][ni] = __builtin_amdgcn_mfma_f32_16x16x32_bf16(af[mi], bfv[ni], acc[mi][ni], 0, 0, 0);
    __syncthreads();          // drains prefetch (latency covered by compute)
    cur ^= 1;
  }

  const int row0 = m0 + wr * 64 + l4 * 4;
  const int col0 = n0 + wc * 64 + l15;
  if constexpr (EPI == 1) {
    float* C = (float*)Cout;
#pragma unroll
    for (int mi = 0; mi < 4; mi++)
#pragma unroll
      for (int ni = 0; ni < 4; ni++)
#pragma unroll
        for (int j = 0; j < 4; j++)
          C[(size_t)(row0 + mi * 16 + j) * N + col0 + ni * 16] = acc[mi][ni][j];
  } else {
    if (n0 < QCOLS + KVCOLS) {
      // RoPE: acc[mi][ni][j] (d = ni*16+l15 < 32) pairs with acc[mi][ni+2][j] (d+32)
#pragma unroll
      for (int mi = 0; mi < 4; mi++)
#pragma unroll
        for (int j = 0; j < 4; j++) {
          int t = (row0 + mi * 16 + j) & (SEQ - 1);
#pragma unroll
          for (int ni = 0; ni < 2; ni++) {
            int d = ni * 16 + l15;
            float c = cosb[t * 32 + d], s = sinb[t * 32 + d];
            float a = acc[mi][ni][j], bb = acc[mi][ni + 2][j];
            acc[mi][ni][j]     = a * c - bb * s;
            acc[mi][ni + 2][j] = bb * c + a * s;
          }
        }
      if (n0 < QCOLS) {
        // Q: fold in softmax scale * log2(e) so k_attn uses exp2 directly
        const float QSC = 0.125f * 1.44269504088896f;
        u16* C = (u16*)Cout;  // Q bf16 [NQROWS][QCOLS], pre-scaled
#pragma unroll
        for (int mi = 0; mi < 4; mi++)
#pragma unroll
          for (int ni = 0; ni < 4; ni++)
#pragma unroll
            for (int j = 0; j < 4; j++)
              C[(size_t)(row0 + mi * 16 + j) * QCOLS + col0 + ni * 16] = f2bf(acc[mi][ni][j] * QSC);
      } else {
        int kc0 = col0 - QCOLS;
#pragma unroll
        for (int mi = 0; mi < 4; mi++)
#pragma unroll
          for (int ni = 0; ni < 4; ni++)
#pragma unroll
            for (int j = 0; j < 4; j++)
              dstK[(size_t)(row0 + mi * 16 + j) * KVCOLS + kc0 + ni * 16] = f2bf(acc[mi][ni][j]);
      }
    } else {
      // V^T: [B][KVCOLS][SEQ]
      int vc0 = col0 - (QCOLS + KVCOLS);
#pragma unroll
      for (int mi = 0; mi < 4; mi++) {
        int row = row0 + mi * 16;
        int b = row >> 11, t = row & (SEQ - 1);
#pragma unroll
        for (int ni = 0; ni < 4; ni++) {
          ushort4 v;
          v.x = f2bf(acc[mi][ni][0]);
          v.y = f2bf(acc[mi][ni][1]);
          v.z = f2bf(acc[mi][ni][2]);
          v.w = f2bf(acc[mi][ni][3]);
          *reinterpret_cast<ushort4*>(&dstV[((size_t)b * KVCOLS + vc0 + ni * 16) * SEQ + t]) = v;
        }
      }
    }
  }
}

// ---------------- causal GQA flash attention (R20 champion, 78.8us) ------
// grid (16, B*NH) = 1024 blocks, block 128 = 2 waves, wave owns 32 q-rows
// of BOTH paired tiles A=bxx, B=31-bxx (same head -> SAME K/V chunks,
// compute-balanced 34 iters/block). Per staged chunk the wave runs TWO
// independent QK->SM->PV chains (dual while kc<=qtA) -> intra-wave ILP.
// (R21 adjacent pairing: 100% dual but 20x imbalance, -31%. R22 32-row
// split chains: balanced+dual but 2x per-step overhead + V conflicts, -22%.
// This pairing is the measured optimum of the family.)
// XCD pinning (FETCH 52->12MB). Q pre-scaled in GEMM. K/V dbuf 32KB LDS
// via global_load_lds (XOR-swizzled). P->A-frag via cvt_pk + permlane32.
__global__ __launch_bounds__(128, 2) void k_attn(const u16* __restrict__ Q,
                                                 const u16* __restrict__ K,
                                                 const u16* __restrict__ VT,
                                                 u16* __restrict__ AO) {
  __shared__ __align__(16) u16 Ks[2][4096];
  __shared__ __align__(16) u16 Vs[2][4096];
  const int tid = threadIdx.x;
  const int w = tid >> 6, l = tid & 63;
  const int lo = l & 31, hi = l >> 5;
  // XCD-pinned work remap (bijective on 1024 ids)
  const int id = blockIdx.y * gridDim.x + blockIdx.x;
  const int bh = (id & 7) * 8 + ((id >> 3) & 7);
  const int bxx = id >> 6;              // 0..15
  const int b = bh >> 5, h = bh & 31, g = h >> 2;
  const int srow = l >> 3, scol = l & 7;

  const u16* Kbase = K + ((size_t)b * SEQ) * KVCOLS + g * 64;
  const u16* Vbase = VT + ((size_t)(b * KVCOLS + g * 64)) * SEQ;

  const int qtA = bxx;              // short tile (<=15)
  const int qtB = 31 - bxx;         // long tile (>=16)
  const int q0A = qtA * 64 + w * 32;
  const int q0B = qtB * 64 + w * 32;
  const int nkc = qtB + 1;
  const int qloc = w * 32 + lo;     // q within a 64-row tile (same for A,B)

  // Q B-frags for both tiles (col=lane&31=q, k=hi*8+e); pre-scaled
  bf16x8 qfA[4], qfB[4];
  {
    const u16* qpA = Q + (size_t)(b * SEQ + q0A + lo) * QCOLS + h * 64 + hi * 8;
    const u16* qpB = Q + (size_t)(b * SEQ + q0B + lo) * QCOLS + h * 64 + hi * 8;
#pragma unroll
    for (int kb = 0; kb < 4; kb++) {
      qfA[kb] = *reinterpret_cast<const bf16x8*>(qpA + kb * 16);
      qfB[kb] = *reinterpret_cast<const bf16x8*>(qpB + kb * 16);
    }
  }
  f32x16 oaccA[2] = {}, oaccB[2] = {};
  float lsA = 0.f, lsB = 0.f;

  // stage chunk 0 -> buf 0 (linear LDS dest, inverse-swizzled global col)
#pragma unroll
  for (int i = 0; i < 4; i++) {
    int r = w * 32 + i * 8 + srow;
    int cs = scol ^ (srow & 7);
    GLOAD16(Kbase + (size_t)r * KVCOLS + cs * 8, &Ks[0][(w * 32 + i * 8) * 64 + l * 8]);
    GLOAD16(Vbase + (size_t)r * SEQ + cs * 8, &Vs[0][(w * 32 + i * 8) * 64 + l * 8]);
  }
  __syncthreads();

  for (int kc = 0; kc < nkc; kc++) {
    const int bi = kc & 1;
    if (kc + 1 < nkc) {
#pragma unroll
      for (int i = 0; i < 4; i++) {
        int r = w * 32 + i * 8 + srow;
        int cs = scol ^ (srow & 7);
        GLOAD16(Kbase + (size_t)((kc + 1) * 64 + r) * KVCOLS + cs * 8,
                &Ks[bi ^ 1][(w * 32 + i * 8) * 64 + l * 8]);
        GLOAD16(Vbase + (size_t)r * SEQ + (kc + 1) * 64 + cs * 8,
                &Vs[bi ^ 1][(w * 32 + i * 8) * 64 + l * 8]);
      }
    }
    const bool doA = (kc <= qtA);
    u32 uA[2][4][2], uB[2][4][2];

    // ---- tile A: QK + softmax (sacc dies before B's is born) ----
    if (doA) {
      f32x16 saccA[2] = {};
      __builtin_amdgcn_s_setprio(1);
#pragma unroll
      for (int t = 0; t < 2; t++)
#pragma unroll
        for (int kb = 0; kb < 4; kb++) {
          int row = t * 32 + lo;
          int slot = (2 * kb + hi) ^ (lo & 7);
          bf16x8 kf = *reinterpret_cast<const bf16x8*>(&Ks[bi][row * 64 + slot * 8]);
          saccA[t] = __builtin_amdgcn_mfma_f32_32x32x16_bf16(kf, qfA[kb], saccA[t], 0, 0, 0);
        }
      __builtin_amdgcn_s_setprio(0);
      const bool diagA = (kc == qtA);
#pragma unroll
      for (int t = 0; t < 2; t++) {
        float pv[16];
#pragma unroll
        for (int r = 0; r < 16; r++) {
          float e = exp2f(saccA[t][r]);
          if (diagA) {
            int kvoff = t * 32 + (r & 3) + 8 * (r >> 2) + 4 * hi;
            if (kvoff > qloc) e = 0.f;
          }
          pv[r] = e; lsA += e;
        }
#pragma unroll
        for (int qd = 0; qd < 4; qd++)
#pragma unroll
          for (int hh = 0; hh < 2; hh++) {
            u32 uu;
            asm("v_cvt_pk_bf16_f32 %0, %1, %2"
                : "=v"(uu) : "v"(pv[qd * 4 + 2 * hh]), "v"(pv[qd * 4 + 2 * hh + 1]));
            uA[t][qd][hh] = uu;
          }
      }
    }

    // ---- tile B: QK + softmax ----
    {
      f32x16 saccB[2] = {};
      __builtin_amdgcn_s_setprio(1);
#pragma unroll
      for (int t = 0; t < 2; t++)
#pragma unroll
        for (int kb = 0; kb < 4; kb++) {
          int row = t * 32 + lo;
          int slot = (2 * kb + hi) ^ (lo & 7);
          bf16x8 kf = *reinterpret_cast<const bf16x8*>(&Ks[bi][row * 64 + slot * 8]);
          saccB[t] = __builtin_amdgcn_mfma_f32_32x32x16_bf16(kf, qfB[kb], saccB[t], 0, 0, 0);
        }
      __builtin_amdgcn_s_setprio(0);
      const bool diagB = (kc == qtB);
#pragma unroll
      for (int t = 0; t < 2; t++) {
        float pv[16];
#pragma unroll
        for (int r = 0; r < 16; r++) {
          float e = exp2f(saccB[t][r]);
          if (diagB) {
            int kvoff = t * 32 + (r & 3) + 8 * (r >> 2) + 4 * hi;
            if (kvoff > qloc) e = 0.f;
          }
          pv[r] = e; lsB += e;
        }
#pragma unroll
        for (int qd = 0; qd < 4; qd++)
#pragma unroll
          for (int hh = 0; hh < 2; hh++) {
            u32 uu;
            asm("v_cvt_pk_bf16_f32 %0, %1, %2"
                : "=v"(uu) : "v"(pv[qd * 4 + 2 * hh]), "v"(pv[qd * 4 + 2 * hh + 1]));
            uB[t][qd][hh] = uu;
          }
      }
    }

    // ---- PV for A then B (independent chains; scheduler interleaves) ----
    if (doA) {
#pragma unroll
      for (int km = 0; km < 4; km++) {
        const int t = km >> 1, p = km & 1;
        u32 a0 = uA[t][2 * p][0], b0 = uA[t][2 * p + 1][0];
        u32 a1 = uA[t][2 * p][1], b1 = uA[t][2 * p + 1][1];
        asm("v_permlane32_swap_b32 %0, %1" : "+v"(a0), "+v"(b0));
        asm("v_permlane32_swap_b32 %0, %1" : "+v"(a1), "+v"(b1));
        union { u32 uu[4]; bf16x8 v; } pa;
        pa.uu[0] = a0; pa.uu[1] = a1; pa.uu[2] = b0; pa.uu[3] = b1;
        __builtin_amdgcn_s_setprio(1);
#pragma unroll
        for (int td = 0; td < 2; td++) {
          int row = td * 32 + lo;
          int slot = (2 * km + hi) ^ (lo & 7);
          bf16x8 vf = *reinterpret_cast<const bf16x8*>(&Vs[bi][row * 64 + slot * 8]);
          oaccA[td] = __builtin_amdgcn_mfma_f32_32x32x16_bf16(pa.v, vf, oaccA[td], 0, 0, 0);
        }
        __builtin_amdgcn_s_setprio(0);
      }
    }
#pragma unroll
    for (int km = 0; km < 4; km++) {
      const int t = km >> 1, p = km & 1;
      u32 a0 = uB[t][2 * p][0], b0 = uB[t][2 * p + 1][0];
      u32 a1 = uB[t][2 * p][1], b1 = uB[t][2 * p + 1][1];
      asm("v_permlane32_swap_b32 %0, %1" : "+v"(a0), "+v"(b0));
      asm("v_permlane32_swap_b32 %0, %1" : "+v"(a1), "+v"(b1));
      union { u32 uu[4]; bf16x8 v; } pa;
      pa.uu[0] = a0; pa.uu[1] = a1; pa.uu[2] = b0; pa.uu[3] = b1;
      __builtin_amdgcn_s_setprio(1);
#pragma unroll
      for (int td = 0; td < 2; td++) {
        int row = td * 32 + lo;
        int slot = (2 * km + hi) ^ (lo & 7);
        bf16x8 vf = *reinterpret_cast<const bf16x8*>(&Vs[bi][row * 64 + slot * 8]);
        oaccB[td] = __builtin_amdgcn_mfma_f32_32x32x16_bf16(pa.v, vf, oaccB[td], 0, 0, 0);
      }
      __builtin_amdgcn_s_setprio(0);
    }
    __syncthreads();
  }

  // epilogues: per-tile denom broadcast + normalize + store
  {
    float tot = lsA;
    tot += __shfl_xor(tot, 32);
#pragma unroll
    for (int r = 0; r < 16; r++) {
      int qr = (r & 3) + 8 * (r >> 2) + 4 * hi;
      float den = __shfl(tot, qr);
      float rv = __builtin_amdgcn_rcpf(den);
      size_t rowbase = (size_t)(b * SEQ + q0A + qr) * QCOLS + h * 64 + lo;
      AO[rowbase]      = f2bf(oaccA[0][r] * rv);
      AO[rowbase + 32] = f2bf(oaccA[1][r] * rv);
    }
  }
  {
    float tot = lsB;
    tot += __shfl_xor(tot, 32);
#pragma unroll
    for (int r = 0; r < 16; r++) {
      int qr = (r & 3) + 8 * (r >> 2) + 4 * hi;
      float den = __shfl(tot, qr);
      float rv = __builtin_amdgcn_rcpf(den);
      size_t rowbase = (size_t)(b * SEQ + q0B + qr) * QCOLS + h * 64 + lo;
      AO[rowbase]      = f2bf(oaccB[0][r] * rv);
      AO[rowbase + 32] = f2bf(oaccB[1][r] * rv);
    }
  }
}

extern "C" void kernel_launch(void* const* d_in, const int* in_sizes, int n_in,
                              void* d_out, int out_size, void* d_ws, size_t ws_size,
                              hipStream_t stream) {
  const float* x    = (const float*)d_in[0];
  const float* cosb = (const float*)d_in[1];
  const float* sinb = (const float*)d_in[2];
  const float* wq   = (const float*)d_in[3];
  const float* wk   = (const float*)d_in[4];
  const float* wv   = (const float*)d_in[5];
  const float* wo   = (const float*)d_in[6];
  float* out = (float*)d_out;

  char* ws = (char*)d_ws;
  size_t off = 0;
  auto alloc = [&](size_t bytes) -> void* {
    void* p = ws + off;
    off += (bytes + 255) & ~(size_t)255;
    return p;
  };
  u16* xb    = (u16*)alloc((size_t)NQROWS * DMODEL * 2);
  u16* wcatT = (u16*)alloc((size_t)NCAT * DMODEL * 2);     // [wq|wk|wv]^T
  u16* woT   = (u16*)alloc((size_t)DMODEL * QCOLS * 2);
  u16* Qb    = (u16*)alloc((size_t)NQROWS * QCOLS * 2);
  u16* Kb    = (u16*)alloc((size_t)NQROWS * KVCOLS * 2);
  u16* VTb   = (u16*)alloc((size_t)BATCH * KVCOLS * SEQ * 2);
  u16* AO    = (u16*)alloc((size_t)NQROWS * QCOLS * 2);

  // merged prep: transposes + x->bf16 in ONE launch (10240 + 8192 blocks)
  k_prep<<<dim3(18432), dim3(256), 0, stream>>>(wq, wk, wv, wo, x, wcatT, woT, xb);

  // fused QKV projection + RoPE epilogue (Q->Qb prescaled, K->Kb, V->VT)
  k_gemm<3><<<dim3(NCAT / 128, NQROWS / 128), 256, 0, stream>>>(
      xb, wcatT, Qb, NQROWS, NCAT, DMODEL, cosb, sinb, Kb, VTb);

  // attention (R20 champion: balanced dual-tile, XCD-pinned)
  k_attn<<<dim3(16, BATCH * NH), 128, 0, stream>>>(Qb, Kb, VTb, AO);

  // output projection -> f32
  k_gemm<1><<<dim3(DMODEL / 128, NQROWS / 128), 256, 0, stream>>>(
      AO, woT, out, NQROWS, DMODEL, QCOLS, nullptr, nullptr, nullptr, nullptr);
}